// Round 1
// baseline (301.238 us; speedup 1.0000x reference)
//
#include <hip/hip_runtime.h>

typedef unsigned short u16;
typedef __attribute__((ext_vector_type(8))) short bf16x8;
typedef __attribute__((ext_vector_type(4))) float f32x4;

#define HID 1024
#define BATCH 4096
#define K3 6144   // 3 * 2048 (hi|hi-or-lo split blocks)
#define NGATE 4096

// ---------- bf16 helpers (bit-level, header-version-proof) ----------
__device__ __forceinline__ u16 f2bf(float f) {
  unsigned int u = __float_as_uint(f);
  u += 0x7FFFu + ((u >> 16) & 1u);   // RNE
  return (u16)(u >> 16);
}
__device__ __forceinline__ float bf2f(u16 h) {
  return __uint_as_float(((unsigned int)h) << 16);
}

__device__ __forceinline__ void load16_to_lds(const void* g, void* l) {
  __builtin_amdgcn_global_load_lds(
      (const __attribute__((address_space(1))) unsigned int*)g,
      (__attribute__((address_space(3))) unsigned int*)l, 16, 0, 0);
}

__device__ __forceinline__ float sigmoid_f(float x) {
  return 1.f / (1.f + __expf(-x));
}
__device__ __forceinline__ float tanh_f(float x) {
  return 1.f - 2.f / (__expf(2.f * x) + 1.f);   // exact at +-inf, no NaN
}

// ---------- pack activations: Bt[m][k'] = [hi(x|h) | lo(x|h) | hi(x|h)] ----------
__global__ void pack_act(const float* __restrict__ x, const float* __restrict__ h,
                         u16* __restrict__ Bt) {
  size_t idx = (size_t)blockIdx.x * 256 + threadIdx.x;  // 4096 * 512 quads
  int m  = (int)(idx >> 9);
  int kq = (int)(idx & 511) << 2;                        // 0..2044 step 4
  const float* src = (kq < 1024) ? (x + (size_t)m * 1024 + kq)
                                 : (h + (size_t)m * 1024 + (kq - 1024));
  float4 v = *(const float4*)src;
  ushort4 hi, lo;
  hi.x = f2bf(v.x); lo.x = f2bf(v.x - bf2f(hi.x));
  hi.y = f2bf(v.y); lo.y = f2bf(v.y - bf2f(hi.y));
  hi.z = f2bf(v.z); lo.z = f2bf(v.z - bf2f(hi.z));
  hi.w = f2bf(v.w); lo.w = f2bf(v.w - bf2f(hi.w));
  u16* row = Bt + (size_t)m * K3;
  *(ushort4*)(row + kq)        = hi;
  *(ushort4*)(row + 2048 + kq) = lo;
  *(ushort4*)(row + 4096 + kq) = hi;
}

// ---------- pack weights: P[n=4h+g][k'] = [hi(W;U) | hi(W;U) | lo(W;U)] (transposed) ----------
__global__ void pack_w(const float* __restrict__ Wf, const float* __restrict__ Wi,
                       const float* __restrict__ Wc, const float* __restrict__ Wo,
                       const float* __restrict__ Uf, const float* __restrict__ Ui,
                       const float* __restrict__ Uc, const float* __restrict__ Uo,
                       u16* __restrict__ P) {
  __shared__ float ldsT[32][33];
  int bid = blockIdx.x;
  int mat = bid >> 10;            // 0..7 : g = mat&3, isU = mat>>2
  int tid = bid & 1023;
  int k0 = (tid >> 5) << 5;       // k-tile * 32
  int h0 = (tid & 31) << 5;       // h-tile * 32
  int g = mat & 3;
  const float* S;
  {
    const float* a = (mat & 1) ? ((mat & 2) ? Wo : Wi) : ((mat & 2) ? Wc : Wf);
    const float* b = (mat & 1) ? ((mat & 2) ? Uo : Ui) : ((mat & 2) ? Uc : Uf);
    S = (mat & 4) ? b : a;
  }
  int kbase = (mat & 4) ? 1024 : 0;

  int t = threadIdx.x;
  {   // read 32x32 f32 tile, coalesced along h; store transposed
    int r0 = t >> 5;              // 0..7
    int c  = t & 31;
#pragma unroll
    for (int j = 0; j < 4; ++j)
      ldsT[c][r0 + 8 * j] = S[(size_t)(k0 + r0 + 8 * j) * 1024 + h0 + c];
  }
  __syncthreads();
  {   // write rows n = 4(h0+c)+g, 32 k each, to the 3 k'-blocks
    int c  = t >> 3;              // 0..31  (h_local)
    int kq = (t & 7) << 2;        // 0..28
    int n  = ((h0 + c) << 2) + g;
    float v0 = ldsT[c][kq + 0], v1 = ldsT[c][kq + 1];
    float v2 = ldsT[c][kq + 2], v3 = ldsT[c][kq + 3];
    ushort4 hi, lo;
    hi.x = f2bf(v0); lo.x = f2bf(v0 - bf2f(hi.x));
    hi.y = f2bf(v1); lo.y = f2bf(v1 - bf2f(hi.y));
    hi.z = f2bf(v2); lo.z = f2bf(v2 - bf2f(hi.z));
    hi.w = f2bf(v3); lo.w = f2bf(v3 - bf2f(hi.w));
    u16* base = P + (size_t)n * K3 + kbase + k0 + kq;
    *(ushort4*)(base)        = hi;   // block0: hi  (x Bhi)
    *(ushort4*)(base + 2048) = hi;   // block1: hi  (x Blo)
    *(ushort4*)(base + 4096) = lo;   // block2: lo  (x Bhi)
  }
}

// ---------- pack biases: bcat[4h+g] = b_g[h] ----------
__global__ void pack_bias(const float* __restrict__ bf, const float* __restrict__ bi,
                          const float* __restrict__ bc, const float* __restrict__ bo,
                          float* __restrict__ bcat) {
  int i = blockIdx.x * 256 + threadIdx.x;
  if (i < NGATE) {
    int h = i >> 2, g = i & 3;
    const float* b = (g == 0) ? bf : (g == 1) ? bi : (g == 2) ? bc : bo;
    bcat[i] = b[h];
  }
}

// ---------- fused GEMM + LSTM epilogue ----------
// G[n, m] = P[n, :] . Bt[m, :]  (K'=6144), n = 4h+g, m = batch
__global__ __launch_bounds__(256, 2) void lstm_gemm(
    const u16* __restrict__ P, const u16* __restrict__ Bt,
    const float* __restrict__ bcat, const float* __restrict__ c_prev,
    float* __restrict__ out) {
  __shared__ __align__(16) u16 As[128 * 32];
  __shared__ __align__(16) u16 Bs[128 * 32];

  const int t = threadIdx.x;
  const int w = t >> 6;
  const int l = t & 63;
  const int n0 = blockIdx.x * 128;
  const int m0 = blockIdx.y * 128;

  f32x4 acc[4][4];
#pragma unroll
  for (int i = 0; i < 4; ++i)
#pragma unroll
    for (int j = 0; j < 4; ++j) acc[i][j] = (f32x4){0.f, 0.f, 0.f, 0.f};

  const int srow  = t >> 2;            // 0..63 (staging row)
  const int skoff = (t & 3) << 3;      // 0,8,16,24
  const u16* gA0 = P  + (size_t)(n0 + srow) * K3 + skoff;
  const u16* gA1 = P  + (size_t)(n0 + 64 + srow) * K3 + skoff;
  const u16* gB0 = Bt + (size_t)(m0 + srow) * K3 + skoff;
  const u16* gB1 = Bt + (size_t)(m0 + 64 + srow) * K3 + skoff;
  u16* lA0 = As + (w << 9);            // wave-uniform base; HW adds lane*16B
  u16* lA1 = As + 2048 + (w << 9);
  u16* lB0 = Bs + (w << 9);
  u16* lB1 = Bs + 2048 + (w << 9);

  const int fr = l & 15;               // fragment row/col
  const int fk = (l >> 4) << 3;        // k-chunk
  const int wr = (w >> 1) << 6;        // wave n-offset: 0/64
  const int wc = (w & 1) << 6;         // wave m-offset: 0/64

  for (int kt = 0; kt < K3; kt += 32) {
    __syncthreads();                   // prev tile fully consumed
    load16_to_lds(gA0 + kt, lA0);
    load16_to_lds(gA1 + kt, lA1);
    load16_to_lds(gB0 + kt, lB0);
    load16_to_lds(gB1 + kt, lB1);
    __syncthreads();                   // vmcnt(0)-drained by compiler before barrier

    bf16x8 aF[4], bF[4];
#pragma unroll
    for (int i = 0; i < 4; ++i)
      aF[i] = *(const bf16x8*)&As[(wr + i * 16 + fr) * 32 + fk];
#pragma unroll
    for (int j = 0; j < 4; ++j)
      bF[j] = *(const bf16x8*)&Bs[(wc + j * 16 + fr) * 32 + fk];
#pragma unroll
    for (int i = 0; i < 4; ++i)
#pragma unroll
      for (int j = 0; j < 4; ++j)
        acc[i][j] = __builtin_amdgcn_mfma_f32_16x16x32_bf16(aF[i], bF[j], acc[i][j], 0, 0, 0);
  }

  // epilogue: lane regs r=0..3 are gates f,i,c,o of (h, m)
  const int n_base = n0 + wr;
  const int m_base = m0 + wc;
#pragma unroll
  for (int i = 0; i < 4; ++i) {
    int nf = n_base + i * 16 + ((l >> 4) << 2);   // multiple of 4
    int hq = nf >> 2;
    float4 b4 = *(const float4*)&bcat[nf];
#pragma unroll
    for (int j = 0; j < 4; ++j) {
      int m = m_base + j * 16 + fr;
      f32x4 a = acc[i][j];
      float ft = sigmoid_f(a[0] + b4.x);
      float it = sigmoid_f(a[1] + b4.y);
      float ct = tanh_f   (a[2] + b4.z);
      float ot = sigmoid_f(a[3] + b4.w);
      float cp = c_prev[(size_t)m * HID + hq];
      float cn = ft * cp + it * ct;
      out[(size_t)m * HID + hq] = ot * tanh_f(cn);
    }
  }
}

extern "C" void kernel_launch(void* const* d_in, const int* in_sizes, int n_in,
                              void* d_out, int out_size, void* d_ws, size_t ws_size,
                              hipStream_t stream) {
  const float* x  = (const float*)d_in[0];
  const float* hp = (const float*)d_in[1];
  const float* cp = (const float*)d_in[2];
  const float* Wf = (const float*)d_in[3];
  const float* Wi = (const float*)d_in[4];
  const float* Wc = (const float*)d_in[5];
  const float* Wo = (const float*)d_in[6];
  const float* Uf = (const float*)d_in[7];
  const float* Ui = (const float*)d_in[8];
  const float* Uc = (const float*)d_in[9];
  const float* Uo = (const float*)d_in[10];
  const float* bf = (const float*)d_in[11];
  const float* bi = (const float*)d_in[12];
  const float* bc = (const float*)d_in[13];
  const float* bo = (const float*)d_in[14];

  const size_t P_BYTES  = (size_t)NGATE * K3 * 2;   // 48 MiB
  const size_t BT_BYTES = (size_t)BATCH * K3 * 2;   // 48 MiB
  u16*   P    = (u16*)d_ws;
  u16*   Bt   = (u16*)((char*)d_ws + P_BYTES);
  float* bcat = (float*)((char*)d_ws + P_BYTES + BT_BYTES);
  float* out  = (float*)d_out;

  pack_act <<<dim3(8192), dim3(256), 0, stream>>>(x, hp, Bt);
  pack_w   <<<dim3(8192), dim3(256), 0, stream>>>(Wf, Wi, Wc, Wo, Uf, Ui, Uc, Uo, P);
  pack_bias<<<dim3(16),   dim3(256), 0, stream>>>(bf, bi, bc, bo, bcat);
  lstm_gemm<<<dim3(32, 32), dim3(256), 0, stream>>>(P, Bt, bcat, cp, out);
}

// Round 2
// 222.068 us; speedup vs baseline: 1.3565x; 1.3565x over previous
//
#include <hip/hip_runtime.h>

typedef unsigned short u16;
typedef __attribute__((ext_vector_type(8))) short bf16x8;
typedef __attribute__((ext_vector_type(4))) float f32x4;

#define HID 1024
#define BATCH 4096
#define K3 6144   // 3 * 2048 (hi | lo | hi split blocks)
#define NGATE 4096
#define BK 32
#define NT 192    // K3 / BK

// ---------- bf16 helpers ----------
__device__ __forceinline__ u16 f2bf(float f) {
  unsigned int u = __float_as_uint(f);
  u += 0x7FFFu + ((u >> 16) & 1u);   // RNE
  return (u16)(u >> 16);
}
__device__ __forceinline__ float bf2f(u16 h) {
  return __uint_as_float(((unsigned int)h) << 16);
}

__device__ __forceinline__ void load16_to_lds(const void* g, void* l) {
  __builtin_amdgcn_global_load_lds(
      (const __attribute__((address_space(1))) unsigned int*)g,
      (__attribute__((address_space(3))) unsigned int*)l, 16, 0, 0);
}

__device__ __forceinline__ float sigmoid_f(float x) {
  return 1.f / (1.f + __expf(-x));
}
__device__ __forceinline__ float tanh_f(float x) {
  return 1.f - 2.f / (__expf(2.f * x) + 1.f);
}

// ---------- pack activations: Bt[m][k'] = [hi(x|h) | lo(x|h) | hi(x|h)] ----------
__global__ void pack_act(const float* __restrict__ x, const float* __restrict__ h,
                         u16* __restrict__ Bt) {
  size_t idx = (size_t)blockIdx.x * 256 + threadIdx.x;
  int m  = (int)(idx >> 9);
  int kq = (int)(idx & 511) << 2;
  const float* src = (kq < 1024) ? (x + (size_t)m * 1024 + kq)
                                 : (h + (size_t)m * 1024 + (kq - 1024));
  float4 v = *(const float4*)src;
  ushort4 hi, lo;
  hi.x = f2bf(v.x); lo.x = f2bf(v.x - bf2f(hi.x));
  hi.y = f2bf(v.y); lo.y = f2bf(v.y - bf2f(hi.y));
  hi.z = f2bf(v.z); lo.z = f2bf(v.z - bf2f(hi.z));
  hi.w = f2bf(v.w); lo.w = f2bf(v.w - bf2f(hi.w));
  u16* row = Bt + (size_t)m * K3;
  *(ushort4*)(row + kq)        = hi;
  *(ushort4*)(row + 2048 + kq) = lo;
  *(ushort4*)(row + 4096 + kq) = hi;
}

// ---------- pack weights: P[n=4h+g][k'] = [hi(W;U) | hi(W;U) | lo(W;U)] ----------
__global__ void pack_w(const float* __restrict__ Wf, const float* __restrict__ Wi,
                       const float* __restrict__ Wc, const float* __restrict__ Wo,
                       const float* __restrict__ Uf, const float* __restrict__ Ui,
                       const float* __restrict__ Uc, const float* __restrict__ Uo,
                       u16* __restrict__ P) {
  __shared__ float ldsT[32][33];
  int bid = blockIdx.x;
  int mat = bid >> 10;
  int tid = bid & 1023;
  int k0 = (tid >> 5) << 5;
  int h0 = (tid & 31) << 5;
  int g = mat & 3;
  const float* S;
  {
    const float* a = (mat & 1) ? ((mat & 2) ? Wo : Wi) : ((mat & 2) ? Wc : Wf);
    const float* b = (mat & 1) ? ((mat & 2) ? Uo : Ui) : ((mat & 2) ? Uc : Uf);
    S = (mat & 4) ? b : a;
  }
  int kbase = (mat & 4) ? 1024 : 0;

  int t = threadIdx.x;
  {
    int r0 = t >> 5;
    int c  = t & 31;
#pragma unroll
    for (int j = 0; j < 4; ++j)
      ldsT[c][r0 + 8 * j] = S[(size_t)(k0 + r0 + 8 * j) * 1024 + h0 + c];
  }
  __syncthreads();
  {
    int c  = t >> 3;
    int kq = (t & 7) << 2;
    int n  = ((h0 + c) << 2) + g;
    float v0 = ldsT[c][kq + 0], v1 = ldsT[c][kq + 1];
    float v2 = ldsT[c][kq + 2], v3 = ldsT[c][kq + 3];
    ushort4 hi, lo;
    hi.x = f2bf(v0); lo.x = f2bf(v0 - bf2f(hi.x));
    hi.y = f2bf(v1); lo.y = f2bf(v1 - bf2f(hi.y));
    hi.z = f2bf(v2); lo.z = f2bf(v2 - bf2f(hi.z));
    hi.w = f2bf(v3); lo.w = f2bf(v3 - bf2f(hi.w));
    u16* base = P + (size_t)n * K3 + kbase + k0 + kq;
    *(ushort4*)(base)        = hi;
    *(ushort4*)(base + 2048) = hi;
    *(ushort4*)(base + 4096) = lo;
  }
}

// ---------- pack biases ----------
__global__ void pack_bias(const float* __restrict__ bf, const float* __restrict__ bi,
                          const float* __restrict__ bc, const float* __restrict__ bo,
                          float* __restrict__ bcat) {
  int i = blockIdx.x * 256 + threadIdx.x;
  if (i < NGATE) {
    int h = i >> 2, g = i & 3;
    const float* b = (g == 0) ? bf : (g == 1) ? bi : (g == 2) ? bc : bo;
    bcat[i] = b[h];
  }
}

// ---------- fused GEMM + LSTM epilogue ----------
// 256x256 tile, BK=32, 8 waves (2M x 4N), 4-deep LDS ring, counted vmcnt(8).
__global__ __launch_bounds__(512, 2) void lstm_gemm(
    const u16* __restrict__ P, const u16* __restrict__ Bt,
    const float* __restrict__ bcat, const float* __restrict__ c_prev,
    float* __restrict__ out) {
  __shared__ __align__(16) u16 As[4][256 * BK];   // 64 KiB
  __shared__ __align__(16) u16 Bs[4][256 * BK];   // 64 KiB

  const int t = threadIdx.x;
  const int w = t >> 6;
  const int l = t & 63;

  // XCD-chunked bijective block swizzle (256 = 8 XCD * 32)
  const int bid = blockIdx.x;
  const int swz = ((bid & 7) << 5) + (bid >> 3);
  const int n0 = (swz & 15) << 8;     // gate-dim tile base
  const int m0 = (swz >> 4) << 8;     // batch tile base

  const int wm = w >> 2;              // 0..1 : wave row-half (A)
  const int wn = w & 3;               // 0..3 : wave col-quarter (B)

  // ---- staging: 4 x global_load_lds per K-tile per wave, swizzled source ----
  const int srow = t >> 2;                               // 0..127
  const int ssl  = (((t & 3) ^ ((srow >> 1) & 3)) << 3); // swizzled 8-u16 slot
  const u16* gA0 = P  + (size_t)(n0 + srow)       * K3 + ssl;
  const u16* gA1 = P  + (size_t)(n0 + 128 + srow) * K3 + ssl;
  const u16* gB0 = Bt + (size_t)(m0 + srow)       * K3 + ssl;
  const u16* gB1 = Bt + (size_t)(m0 + 128 + srow) * K3 + ssl;
  const int ldw0 = w << 9;            // wave-uniform LDS dest (u16): w*1024B
  const int ldw1 = 4096 + (w << 9);   // rows 128..255 half

  // ---- fragment read offsets (loop-invariant, swizzled) ----
  const int fr = l & 15;
  const int sl = l >> 4;
  int offA[8], offB[4];
#pragma unroll
  for (int i = 0; i < 8; ++i) {
    int ar = (wm << 7) + i * 16 + fr;
    offA[i] = ar * BK + ((sl ^ ((ar >> 1) & 3)) << 3);
  }
#pragma unroll
  for (int j = 0; j < 4; ++j) {
    int br = (wn << 6) + j * 16 + fr;
    offB[j] = br * BK + ((sl ^ ((br >> 1) & 3)) << 3);
  }

  f32x4 acc[8][4];
#pragma unroll
  for (int i = 0; i < 8; ++i)
#pragma unroll
    for (int j = 0; j < 4; ++j) acc[i][j] = (f32x4){0.f, 0.f, 0.f, 0.f};

  // ---- prologue: stage K-tiles 0,1,2 into bufs 0,1,2 ----
#pragma unroll
  for (int pt = 0; pt < 3; ++pt) {
    const int kt = pt * BK;
    load16_to_lds(gA0 + kt, &As[pt][ldw0]);
    load16_to_lds(gA1 + kt, &As[pt][ldw1]);
    load16_to_lds(gB0 + kt, &Bs[pt][ldw0]);
    load16_to_lds(gB1 + kt, &Bs[pt][ldw1]);
  }
  asm volatile("s_waitcnt vmcnt(8)" ::: "memory");   // tile 0 landed; 1,2 in flight
  __builtin_amdgcn_s_barrier();

  // ---- main loop: 192 K-tiles, unrolled x4 so buffer indices are static ----
  for (int t4 = 0; t4 < NT; t4 += 4) {
#pragma unroll
    for (int u = 0; u < 4; ++u) {
      const int tt  = t4 + u;
      const int pfi = tt + 3;
      const int pkt = (pfi < NT ? pfi : NT - 1) * BK;  // clamped tail prefetch
      const int pc  = (u + 3) & 3;

      // ---- phase A: row-half 0 ----
      bf16x8 aF[4], bF[4];
#pragma unroll
      for (int i = 0; i < 4; ++i) aF[i] = *(const bf16x8*)&As[u][offA[i]];
#pragma unroll
      for (int j = 0; j < 4; ++j) bF[j] = *(const bf16x8*)&Bs[u][offB[j]];
      load16_to_lds(gA0 + pkt, &As[pc][ldw0]);
      load16_to_lds(gA1 + pkt, &As[pc][ldw1]);
      __builtin_amdgcn_s_barrier();
      asm volatile("s_waitcnt lgkmcnt(0)" ::: "memory");
      __builtin_amdgcn_sched_barrier(0);
      __builtin_amdgcn_s_setprio(1);
#pragma unroll
      for (int i = 0; i < 4; ++i)
#pragma unroll
        for (int j = 0; j < 4; ++j)
          acc[i][j] = __builtin_amdgcn_mfma_f32_16x16x32_bf16(aF[i], bF[j], acc[i][j], 0, 0, 0);
      __builtin_amdgcn_s_setprio(0);
      __builtin_amdgcn_s_barrier();

      // ---- phase B: row-half 1 ----
      bf16x8 aG[4];
#pragma unroll
      for (int i = 0; i < 4; ++i) aG[i] = *(const bf16x8*)&As[u][offA[4 + i]];
      load16_to_lds(gB0 + pkt, &Bs[pc][ldw0]);
      load16_to_lds(gB1 + pkt, &Bs[pc][ldw1]);
      __builtin_amdgcn_s_barrier();
      asm volatile("s_waitcnt lgkmcnt(0)" ::: "memory");
      __builtin_amdgcn_sched_barrier(0);
      __builtin_amdgcn_s_setprio(1);
#pragma unroll
      for (int i = 0; i < 4; ++i)
#pragma unroll
        for (int j = 0; j < 4; ++j)
          acc[4 + i][j] = __builtin_amdgcn_mfma_f32_16x16x32_bf16(aG[i], bF[j], acc[4 + i][j], 0, 0, 0);
      __builtin_amdgcn_s_setprio(0);
      // counted drain: tile tt+1 landed, tiles tt+2 & tt+3 (8 loads) stay in flight
      asm volatile("s_waitcnt vmcnt(8)" ::: "memory");
      __builtin_amdgcn_s_barrier();
    }
  }

  // ---- epilogue: lane regs r=0..3 are gates f,i,c,o of (h, m) ----
  const int n_base = n0 + (wm << 7);
  const int m_base = m0 + (wn << 6);
#pragma unroll
  for (int i = 0; i < 8; ++i) {
    int nf = n_base + i * 16 + ((l >> 4) << 2);
    int hq = nf >> 2;
    float4 b4 = *(const float4*)&bcat[nf];
#pragma unroll
    for (int j = 0; j < 4; ++j) {
      int m = m_base + j * 16 + fr;
      f32x4 a = acc[i][j];
      float ft = sigmoid_f(a[0] + b4.x);
      float it = sigmoid_f(a[1] + b4.y);
      float ct = tanh_f   (a[2] + b4.z);
      float ot = sigmoid_f(a[3] + b4.w);
      float cp = c_prev[(size_t)m * HID + hq];
      float cn = ft * cp + it * ct;
      out[(size_t)m * HID + hq] = ot * tanh_f(cn);
    }
  }
}

extern "C" void kernel_launch(void* const* d_in, const int* in_sizes, int n_in,
                              void* d_out, int out_size, void* d_ws, size_t ws_size,
                              hipStream_t stream) {
  const float* x  = (const float*)d_in[0];
  const float* hp = (const float*)d_in[1];
  const float* cp = (const float*)d_in[2];
  const float* Wf = (const float*)d_in[3];
  const float* Wi = (const float*)d_in[4];
  const float* Wc = (const float*)d_in[5];
  const float* Wo = (const float*)d_in[6];
  const float* Uf = (const float*)d_in[7];
  const float* Ui = (const float*)d_in[8];
  const float* Uc = (const float*)d_in[9];
  const float* Uo = (const float*)d_in[10];
  const float* bf = (const float*)d_in[11];
  const float* bi = (const float*)d_in[12];
  const float* bc = (const float*)d_in[13];
  const float* bo = (const float*)d_in[14];

  const size_t P_BYTES  = (size_t)NGATE * K3 * 2;
  const size_t BT_BYTES = (size_t)BATCH * K3 * 2;
  u16*   Pw   = (u16*)d_ws;
  u16*   Bt   = (u16*)((char*)d_ws + P_BYTES);
  float* bcat = (float*)((char*)d_ws + P_BYTES + BT_BYTES);
  float* out  = (float*)d_out;

  pack_act <<<dim3(8192), dim3(256), 0, stream>>>(x, hp, Bt);
  pack_w   <<<dim3(8192), dim3(256), 0, stream>>>(Wf, Wi, Wc, Wo, Uf, Ui, Uc, Uo, Pw);
  pack_bias<<<dim3(16),   dim3(256), 0, stream>>>(bf, bi, bc, bo, bcat);
  lstm_gemm<<<dim3(256),  dim3(512), 0, stream>>>(Pw, Bt, bcat, cp, out);
}